// Round 3
// baseline (300.116 us; speedup 1.0000x reference)
//
#include <hip/hip_runtime.h>

// Problem constants (from reference)
#define N1C 50000
#define NNC 16
#define NIC 64
#define NDC 128
#define QB  8     // queries per block
#define MR  128   // QB*NN rows per block

typedef __bf16 bf16x8 __attribute__((ext_vector_type(8)));
typedef float f32x4 __attribute__((ext_vector_type(4)));

#if defined(__has_builtin)
#if __has_builtin(__builtin_amdgcn_cvt_pk_bf16_f32)
#define HAVE_PK_BF16 1
#endif
#endif

#ifdef HAVE_PK_BF16
typedef __bf16 bf16x2 __attribute__((ext_vector_type(2)));
static __device__ __forceinline__ unsigned int pkbf(float a, float b) {
    bf16x2 r = __builtin_amdgcn_cvt_pk_bf16_f32(a, b);
    return __builtin_bit_cast(unsigned int, r);
}
#else
static __device__ __forceinline__ unsigned short f2bf_sw(float f) {
    unsigned int u = __builtin_bit_cast(unsigned int, f);
    u += 0x7fffu + ((u >> 16) & 1u);
    return (unsigned short)(u >> 16);
}
static __device__ __forceinline__ unsigned int pkbf(float a, float b) {
    return (unsigned int)f2bf_sw(a) | ((unsigned int)f2bf_sw(b) << 16);
}
#endif

static __device__ __forceinline__ unsigned short bf1(float a) {
    return (unsigned short)pkbf(a, 0.f);
}

static __device__ __forceinline__ float elu(float x) {
    return x > 0.f ? x : __expf(x) - 1.f;
}

// ---- prep: plain bf16 W^T images (stride 128) into ws. W^T[d][k] = W[k][d]. ----
__global__ void prep_w(const float* __restrict__ W1, const float* __restrict__ W2,
                       unsigned short* __restrict__ wsW) {
    const int idx = blockIdx.x * 256 + threadIdx.x;   // 0 .. 32767
    const int m   = idx >> 14;
    const int o   = idx & 16383;
    const int d   = o >> 7;
    const int k   = o & 127;
    const float* W = m ? W2 : W1;
    wsW[idx] = bf1(W[(size_t)k * NDC + d]);
}

__global__ __launch_bounds__(256, 4)
void fused_knn_mlp(const float* __restrict__ features1,
                   const float* __restrict__ features2,
                   const float* __restrict__ x1,
                   const float* __restrict__ x2,
                   const int*   __restrict__ topk,
                   const float* __restrict__ b1,
                   const float* __restrict__ b2,
                   const float* __restrict__ radius,
                   const unsigned short* __restrict__ wsW,
                   float* __restrict__ out)
{
    // Single 32 KB tile: layer-1 A (128x128 bf16) then, per-wave in place, h1.
    // XOR swizzle: 16B chunk c of row r stored at chunk (c ^ (r&15)).
    __shared__ unsigned short sX[MR * NDC];
    __shared__ float sWgt[MR];
    __shared__ int   sIdx[MR];
    __shared__ float sB1[NDC];
    __shared__ float sB2[NDC];

    const int tid  = threadIdx.x;
    const int blk  = blockIdx.x;
    const int lane = tid & 63;
    const int wave = tid >> 6;
    const int quad = lane >> 4;
    const int l16  = lane & 15;

    // ---- phase 0: neighbor indices, distance weights, biases ----
    if (tid < MR) {
        const int q   = tid >> 4;
        const int nq  = blk * QB + q;
        const int idx = topk[nq * NNC + (tid & 15)];
        sIdx[tid] = idx;
        const float r = radius[0];
        const float inv2r2 = 1.f / (2.f * r * r);
        const float dx = x2[idx * 3 + 0] - x1[nq * 3 + 0];
        const float dy = x2[idx * 3 + 1] - x1[nq * 3 + 1];
        const float dz = x2[idx * 3 + 2] - x1[nq * 3 + 2];
        const float w = __expf(-(dx * dx + dy * dy + dz * dz) * inv2r2);
        sWgt[tid] = (idx == 0) ? 0.f : w;
    } else {
        const int d = tid - 128;
        sB1[d] = b1[d];
        sB2[d] = b2[d];
    }
    __syncthreads();

    // ---- stage A tile rows: [features2[idx_r] (cols 0..63) | features1[nq] (cols 64..127)] ----
    // features2 part: 128 rows x 16 float4-chunks (8B bf16 half-chunks), swizzled
    #pragma unroll
    for (int jj = 0; jj < 8; ++jj) {
        const int e  = jj * 256 + tid;   // 0..2047
        const int r  = e >> 4;
        const int c4 = e & 15;           // float4 index within 64-float f2 row
        const float4 v = *(const float4*)(features2 + (size_t)sIdx[r] * NIC + c4 * 4);
        uint2 p;
        p.x = pkbf(v.x, v.y);
        p.y = pkbf(v.z, v.w);
        const int chunk = (c4 >> 1) ^ (r & 15);
        *(uint2*)&sX[r * NDC + chunk * 8 + (c4 & 1) * 4] = p;
    }
    // features1 part: q = tid>>5, c4 = tid&15, h = (tid>>4)&1 selects 8-row half
    {
        const int q = tid >> 5;
        const int c4 = tid & 15;
        const int h = (tid >> 4) & 1;
        const float4 v = *(const float4*)(features1 + (size_t)(blk * QB + q) * NIC + c4 * 4);
        uint2 p;
        p.x = pkbf(v.x, v.y);
        p.y = pkbf(v.z, v.w);
        #pragma unroll
        for (int rr = 0; rr < 8; ++rr) {
            const int r = q * 16 + h * 8 + rr;
            const int chunk = (8 + (c4 >> 1)) ^ (r & 15);
            *(uint2*)&sX[r * NDC + chunk * 8 + (c4 & 1) * 4] = p;
        }
    }
    __syncthreads();

    const unsigned short* wsW1 = wsW;          // W1^T [d][k], bf16, stride 128
    const unsigned short* wsW2 = wsW + 16384;  // W2^T

    // ---- layer 1: acc = A @ W1 + b1 (bias folded into acc init; B-frags from global/L1) ----
    f32x4 acc[2][8];
    #pragma unroll
    for (int nt = 0; nt < 8; ++nt) {
        const float bb = sB1[nt * 16 + l16];
        acc[0][nt] = (f32x4){bb, bb, bb, bb};
        acc[1][nt] = acc[0][nt];
    }

    #pragma unroll
    for (int ks = 0; ks < 4; ++ks) {
        const int k0 = ks * 32 + quad * 8;
        const int pc = ((ks * 4 + quad) ^ l16) * 8;   // swizzled chunk offset (shorts)
        const bf16x8 a0 = *(const bf16x8*)&sX[(wave * 32 + l16) * NDC + pc];
        const bf16x8 a1 = *(const bf16x8*)&sX[(wave * 32 + 16 + l16) * NDC + pc];
        #pragma unroll
        for (int nt = 0; nt < 8; ++nt) {
            const bf16x8 b = *(const bf16x8*)(wsW1 + (nt * 16 + l16) * NDC + k0);
            acc[0][nt] = __builtin_amdgcn_mfma_f32_16x16x32_bf16(a0, b, acc[0][nt], 0, 0, 0);
            acc[1][nt] = __builtin_amdgcn_mfma_f32_16x16x32_bf16(a1, b, acc[1][nt], 0, 0, 0);
        }
    }

    // ---- h1 = elu(acc) -> sX, in place over the wave's OWN 32 rows (no barrier needed) ----
    // C/D layout: col = nt*16 + l16, row(within tile) = quad*4 + reg  [m89/m91]
    #pragma unroll
    for (int mt = 0; mt < 2; ++mt) {
        const int q = wave * 2 + mt;
        #pragma unroll
        for (int nt = 0; nt < 8; ++nt) {
            const int col = nt * 16 + l16;
            const int chunk = (nt * 2 + (l16 >> 3));
            const int o = l16 & 7;
            #pragma unroll
            for (int reg = 0; reg < 4; ++reg) {
                const int row = q * 16 + quad * 4 + reg;
                sX[row * NDC + (chunk ^ (row & 15)) * 8 + o] = bf1(elu(acc[mt][nt][reg]));
            }
        }
    }

    // ---- layer 2: acc = h1 @ W2 + b2 (reads only own 32 rows; no barrier) ----
    f32x4 acc2[2][8];
    #pragma unroll
    for (int nt = 0; nt < 8; ++nt) {
        const float bb = sB2[nt * 16 + l16];
        acc2[0][nt] = (f32x4){bb, bb, bb, bb};
        acc2[1][nt] = acc2[0][nt];
    }
    #pragma unroll
    for (int ks = 0; ks < 4; ++ks) {
        const int k0 = ks * 32 + quad * 8;
        const int pc = ((ks * 4 + quad) ^ l16) * 8;
        const bf16x8 a0 = *(const bf16x8*)&sX[(wave * 32 + l16) * NDC + pc];
        const bf16x8 a1 = *(const bf16x8*)&sX[(wave * 32 + 16 + l16) * NDC + pc];
        #pragma unroll
        for (int nt = 0; nt < 8; ++nt) {
            const bf16x8 b = *(const bf16x8*)(wsW2 + (nt * 16 + l16) * NDC + k0);
            acc2[0][nt] = __builtin_amdgcn_mfma_f32_16x16x32_bf16(a0, b, acc2[0][nt], 0, 0, 0);
            acc2[1][nt] = __builtin_amdgcn_mfma_f32_16x16x32_bf16(a1, b, acc2[1][nt], 0, 0, 0);
        }
    }

    // ---- epilogue: out[q][d] = sum_k w[k] * elu(h2[k][d]) ----
    #pragma unroll
    for (int mt = 0; mt < 2; ++mt) {
        const int q = wave * 2 + mt;
        const float4 wv = *(const float4*)&sWgt[q * 16 + quad * 4];
        #pragma unroll
        for (int nt = 0; nt < 8; ++nt) {
            const int col = nt * 16 + l16;
            float s = elu(acc2[mt][nt][0]) * wv.x
                    + elu(acc2[mt][nt][1]) * wv.y
                    + elu(acc2[mt][nt][2]) * wv.z
                    + elu(acc2[mt][nt][3]) * wv.w;
            s += __shfl_xor(s, 16, 64);
            s += __shfl_xor(s, 32, 64);
            if (lane < 16) {
                out[(size_t)(blk * QB + q) * NDC + col] = s;
            }
        }
    }
}

extern "C" void kernel_launch(void* const* d_in, const int* in_sizes, int n_in,
                              void* d_out, int out_size, void* d_ws, size_t ws_size,
                              hipStream_t stream) {
    const float* features1 = (const float*)d_in[0];
    const float* features2 = (const float*)d_in[1];
    const float* x1        = (const float*)d_in[2];
    const float* x2        = (const float*)d_in[3];
    // d_in[4], d_in[5] = nuv1, nuv2 (unused by reference)
    const int*   topk      = (const int*)d_in[6];
    const float* W1        = (const float*)d_in[7];
    const float* b1        = (const float*)d_in[8];
    const float* W2        = (const float*)d_in[9];
    const float* b2        = (const float*)d_in[10];
    const float* radius    = (const float*)d_in[11];
    float* out = (float*)d_out;
    unsigned short* wsW = (unsigned short*)d_ws;   // 32768 shorts = 64 KB

    prep_w<<<dim3(128), 256, 0, stream>>>(W1, W2, wsW);
    fused_knn_mlp<<<dim3(N1C / QB), 256, 0, stream>>>(features1, features2, x1, x2, topk,
                                                      b1, b2, radius, wsW, out);
}